// Round 10
// baseline (59.262 us; speedup 1.0000x reference)
//
#include <hip/hip_runtime.h>
#include <hip/hip_bf16.h>

typedef __attribute__((ext_vector_type(4))) float f4v;
typedef __attribute__((ext_vector_type(16))) float f16v;
typedef __attribute__((ext_vector_type(4))) unsigned short u16x4;
typedef __attribute__((ext_vector_type(8))) unsigned short u16x8;
typedef __attribute__((ext_vector_type(4))) unsigned int u32x4;
typedef __attribute__((ext_vector_type(8))) __bf16 bf16x8;
typedef __attribute__((ext_vector_type(8))) _Float16 h8v;

#define D_MODEL 1024
#define HDIM 64
#define TSEQ 4096
#define QB 32
#define KVB 64
// 1/sqrt(HDIM) * log2(e), folded into Q at projection
#define QSCALE 0.18033688011112042f

__device__ __forceinline__ unsigned short f2bf(float f) {
    union { float f; unsigned u; } v; v.f = f;
    unsigned r = v.u + 0x7FFFu + ((v.u >> 16) & 1u);
    return (unsigned short)(r >> 16);
}
__device__ __forceinline__ bf16x8 ld8(const unsigned short* p) {
    return __builtin_bit_cast(bf16x8, *(const u16x8*)p);
}
__device__ __forceinline__ h8v ldh8(const unsigned short* p) {
    return __builtin_bit_cast(h8v, *(const u16x8*)p);
}
__device__ __forceinline__ f4v mfma16f(h8v a, h8v b, f4v c) {
    return __builtin_amdgcn_mfma_f32_16x16x32_f16(a, b, c, 0, 0, 0);
}
__device__ __forceinline__ f16v mfma32(bf16x8 a, bf16x8 b, f16v c) {
    return __builtin_amdgcn_mfma_f32_32x32x16_bf16(a, b, c, 0, 0, 0);
}
__device__ __forceinline__ unsigned cvtpk(float a, float b) {
    unsigned r;
    asm("v_cvt_pk_bf16_f32 %0, %1, %2" : "=v"(r) : "v"(a), "v"(b));
    return r;
}
__device__ __forceinline__ void pswap(unsigned& a, unsigned& b) {
    asm("v_permlane32_swap_b32 %0, %1" : "+v"(a), "+v"(b));
}
__device__ __forceinline__ h8v pack8(f4v a, f4v b) {
    unsigned p0 = __builtin_bit_cast(unsigned, __builtin_amdgcn_cvt_pkrtz(a[0], a[1]));
    unsigned p1 = __builtin_bit_cast(unsigned, __builtin_amdgcn_cvt_pkrtz(a[2], a[3]));
    unsigned p2 = __builtin_bit_cast(unsigned, __builtin_amdgcn_cvt_pkrtz(b[0], b[1]));
    unsigned p3 = __builtin_bit_cast(unsigned, __builtin_amdgcn_cvt_pkrtz(b[2], b[3]));
    u32x4 u = {p0, p1, p2, p3};
    return __builtin_bit_cast(h8v, u);
}

// ---------- fused prep: x -> fp16 fragment order; W -> fp16 fragment order ----------
// Blocks < 2048: x conversion. 32768 frag-units (kstep 32 x strip 1024), 8192 waves,
//   4 units each. Reads 100%-line-utilized (one 128B line per row per unit);
//   writes perfectly coalesced (wave writes contiguous 1KB).
//   xf[kstep][strip][lane][8]: elem = x[strip*16+(l&15)][kstep*32+8*(l>>4)+j]
// Blocks >= 2048: W frag conversion (prep_wf logic), 64 blocks x 3072 elems.
//   Wf[((m*32+kstep)*4+nf)<<9 | lane*8 | j] = W_m[k][n], k=kstep*32+8*(l>>4)+j, n=nf*16+(l&15)
__global__ void fused_prep(const float* __restrict__ x, const float* __restrict__ Wq,
                           const float* __restrict__ Wk, const float* __restrict__ Wv,
                           unsigned short* __restrict__ Wf, unsigned short* __restrict__ xf)
{
    const int bid = blockIdx.x;
    if (bid < 2048) {
        const int gw = bid * 4 + (threadIdx.x >> 6);
        const int l = threadIdx.x & 63;
        const int row_l = l & 15, kc = l >> 4;
#pragma unroll
        for (int rep = 0; rep < 4; ++rep) {
            const int u = gw + rep * 8192;
            const int strip = u >> 5, kstep = u & 31;
            const float* p = x + (size_t)(strip * 16 + row_l) * D_MODEL + kstep * 32 + 8 * kc;
            f4v a = *(const f4v*)p;
            f4v b = *(const f4v*)(p + 4);
            h8v pk = pack8(a, b);
            *(u16x8*)(xf + (((size_t)kstep * 1024 + strip) << 9) + l * 8) =
                __builtin_bit_cast(u16x8, pk);
        }
    } else {
        const int base = (bid - 2048) * 3072;
#pragma unroll
        for (int e = 0; e < 12; ++e) {
            int idx = base + e * 256 + threadIdx.x;
            int j = idx & 7, lane = (idx >> 3) & 63, nf = (idx >> 9) & 3,
                kstep = (idx >> 11) & 31, m = idx >> 16;
            int k = kstep * 32 + 8 * (lane >> 4) + j;
            int n = nf * 16 + (lane & 15);
            const float* W = (m == 0) ? Wq : (m == 1) ? Wk : Wv;
            _Float16 hv = (_Float16)W[k * 64 + n];
            Wf[idx] = __builtin_bit_cast(unsigned short, hv);
        }
    }
}

// ---------- QKV projection from fragment-order inputs ----------
// 512 blocks (strip-quad 256 x col-half 2) x 256 thr, 2 blocks/CU.
// Wave = one 16-row strip x 6 col-frags (acc[6]). x-frags: DIRECT coalesced
// ldh8 from xf (L3-hot, no barrier on the x path). W: per-k-tile (BK=128)
// glds-staged into LDS, shared by the 4 strips; the per-iter barrier drains
// only L2-latency W loads -> easily covered by the body.
__global__ __launch_bounds__(256, 2)
void projf(const unsigned short* __restrict__ xf, const unsigned short* __restrict__ Wf,
           const float* __restrict__ bq, const float* __restrict__ bk,
           const float* __restrict__ bv,
           unsigned short* __restrict__ Qf, unsigned short* __restrict__ Kf,
           unsigned short* __restrict__ Vf)
{
    __shared__ unsigned short wlds[2][6][4][512];   // [buf][frag][ks][lane*8] = 48KB

    const int tid = threadIdx.x;
    const int w = tid >> 6, l = tid & 63;
    const int half = blockIdx.x & 1;
    const int strip = (blockIdx.x >> 1) * 4 + w;

    f4v acc[6];
#pragma unroll
    for (int f = 0; f < 6; ++f) acc[f] = (f4v)0.f;

    // stage W chunk for k-tile t (6 frags x 4 ksteps x 1KB = 24KB) via glds.
    // dest wave-uniform base; HW appends lane*16B -> lands at wlds[..][l*8]. 
    auto stage = [&](int buf, int t) {
#pragma unroll
        for (int j = 0; j < 6; ++j) {
            const int ci = w * 6 + j;          // 0..23
            const int f = ci >> 2, ks = ci & 3;
            const int cf = half * 6 + f;
            const unsigned short* src =
                Wf + ((((cf >> 2) * 32 + (t * 4 + ks)) * 4 + (cf & 3)) << 9) + l * 8;
            __builtin_amdgcn_global_load_lds(
                (const __attribute__((address_space(1))) unsigned*)src,
                (__attribute__((address_space(3))) unsigned*)&wlds[buf][f][ks][0],
                16, 0, 0);
        }
    };

    stage(0, 0);
    __syncthreads();

#pragma unroll
    for (int t = 0; t < 8; ++t) {
        if (t < 7) stage((t + 1) & 1, t + 1);
        const int b = t & 1;
#pragma unroll
        for (int ks = 0; ks < 4; ++ks) {
            h8v xa = ldh8(xf + (((size_t)(t * 4 + ks) * 1024 + strip) << 9) + l * 8);
#pragma unroll
            for (int f = 0; f < 6; ++f) {
                h8v bw = ldh8(&wlds[b][f][ks][l * 8]);
                acc[f] = mfma16f(xa, bw, acc[f]);
            }
        }
        __syncthreads();
    }

    const float* bias[3] = {bq, bk, bv};
    const int rowb = strip * 16 + 4 * (l >> 4);
    const int b = rowb >> 12, tok0 = rowb & 4095;
#pragma unroll
    for (int f = 0; f < 6; ++f) {
        const int cf = half * 6 + f;
        const int m = cf >> 2, nf = cf & 3;
        const int d = nf * 16 + (l & 15);
        const float bb = bias[m][d];
        if (m == 0) {
            const int qtile = tok0 >> 5;
            const int ksq = d >> 4, hq = (d >> 3) & 1, jq = d & 7;
#pragma unroll
            for (int r4 = 0; r4 < 4; ++r4) {
                int cq = (tok0 & 31) + r4;
                Qf[(((size_t)(b * 128 + qtile) * 4 + ksq) << 9) + (32 * hq + cq) * 8 + jq] =
                    f2bf((acc[f][r4] + bb) * QSCALE);
            }
        } else if (m == 1) {
            const int t = tok0 >> 6, tb = (tok0 >> 5) & 1;
            const int ksk = d >> 4, hk = (d >> 3) & 1, jk = d & 7;
#pragma unroll
            for (int r4 = 0; r4 < 4; ++r4) {
                int ck = (tok0 & 31) + r4;
                Kf[(((size_t)((b * 64 + t) * 8 + tb * 4 + ksk)) << 9) + (32 * hk + ck) * 8 + jk] =
                    f2bf(acc[f][r4] + bb);
            }
        } else {
            // Vf element (lane', j) = V[kv = t*64 + 16ku + 8hv + j][dv = 32td + c']
            const int t = tok0 >> 6, ku = (tok0 >> 4) & 3, hv = (tok0 >> 3) & 1, jv = tok0 & 7;
            const int cv = d & 31, td = d >> 5;
            u16x4 pk;
#pragma unroll
            for (int r4 = 0; r4 < 4; ++r4) pk[r4] = f2bf(acc[f][r4] + bb);
            *(u16x4*)(Vf + (((size_t)((b * 64 + t) * 8 + td * 4 + ku)) << 9) +
                      (32 * hv + cv) * 8 + jv) = pk;
        }
    }
}

// ---------- flash attention ----------
// 256 blocks (4 batch x 64 q-tile PAIRS {pr, 127-pr}: constant work) x 8 waves.
// batch = bid&3 -> each XCD sees one batch -> K/V L2-resident.
// Wave g handles kv tiles t = g, g+8, ... for BOTH q-tiles -> balanced per wave.
// All operand loads are 1KB coalesced ld8 from fragment-order Qf/Kf/Vf.
struct TState { float m, l; f16v o0, o1; };

__device__ __forceinline__ void run_tile(const unsigned short* __restrict__ Qf,
                                         const unsigned short* __restrict__ Kf,
                                         const unsigned short* __restrict__ Vf,
                                         int batch, int qt, int g8, int l, int h, int c,
                                         TState& st)
{
    const int NT = (qt >> 1) + 1;
    st.m = -1e30f; st.l = 0.f; st.o0 = (f16v)0.f; st.o1 = (f16v)0.f;

    bf16x8 qf[4];
    const unsigned short* qp = Qf + (((size_t)(batch * 128 + qt) * 4) << 9) + l * 8;
#pragma unroll
    for (int ks = 0; ks < 4; ++ks) qf[ks] = ld8(qp + (ks << 9));

    if (g8 >= NT) return;

    auto kload = [&](bf16x8(&kr)[2][4], int t_) {
        const unsigned short* p = Kf + (((size_t)(batch * 64 + t_) * 8) << 9) + l * 8;
#pragma unroll
        for (int tb = 0; tb < 2; ++tb)
#pragma unroll
            for (int ks = 0; ks < 4; ++ks)
                kr[tb][ks] = ld8(p + ((tb * 4 + ks) << 9));
    };

    auto body = [&](bf16x8(&kr)[2][4], bf16x8(&kn)[2][4], int t_) {
        bf16x8 vr[2][4];
        {
            const unsigned short* p = Vf + (((size_t)(batch * 64 + t_) * 8) << 9) + l * 8;
#pragma unroll
            for (int td = 0; td < 2; ++td)
#pragma unroll
                for (int ku = 0; ku < 4; ++ku)
                    vr[td][ku] = ld8(p + ((td * 4 + ku) << 9));
        }
        // S^T = K Q^T
        f16v sacc[2];
        sacc[0] = (f16v)0.f; sacc[1] = (f16v)0.f;
#pragma unroll
        for (int ks = 0; ks < 4; ++ks) {
            sacc[0] = mfma32(kr[0][ks], qf[ks], sacc[0]);
            sacc[1] = mfma32(kr[1][ks], qf[ks], sacc[1]);
        }
        int tn = t_ + 8; if (tn > NT - 1) tn = NT - 1;
        kload(kn, tn);
        if (t_ == NT - 1) {   // causal mask on diagonal tile
            const int off = qt * QB - t_ * KVB;
#pragma unroll
            for (int tb = 0; tb < 2; ++tb)
#pragma unroll
                for (int r = 0; r < 16; ++r) {
                    int mv = 32 * tb + (r & 3) + 8 * (r >> 2) + 4 * h - off;
                    if (mv > c) sacc[tb][r] = -1e30f;
                }
        }
        // online softmax (exp2 domain)
        float pm = -1e30f;
#pragma unroll
        for (int tb = 0; tb < 2; ++tb)
#pragma unroll
            for (int r = 0; r < 16; ++r) pm = fmaxf(pm, sacc[tb][r]);
        pm = fmaxf(pm, __shfl_xor(pm, 32));
        const float mnew = fmaxf(st.m, pm);
        const float sc = exp2f(st.m - mnew);
        st.m = mnew;
        float rs = 0.f;
        float p[2][16];
#pragma unroll
        for (int tb = 0; tb < 2; ++tb)
#pragma unroll
            for (int r = 0; r < 16; ++r) {
                float e = exp2f(sacc[tb][r] - mnew);
                p[tb][r] = e; rs += e;
            }
        rs += __shfl_xor(rs, 32);
        st.l = st.l * sc + rs;
#pragma unroll
        for (int r = 0; r < 16; ++r) { st.o0[r] *= sc; st.o1[r] *= sc; }
        // P (C-layout) -> frag via cvt_pk + permlane32_swap
        bf16x8 pa[4];
#pragma unroll
        for (int tb = 0; tb < 2; ++tb) {
            unsigned wp[8];
#pragma unroll
            for (int i = 0; i < 8; ++i) wp[i] = cvtpk(p[tb][2 * i], p[tb][2 * i + 1]);
            pswap(wp[0], wp[2]); pswap(wp[1], wp[3]);
            pswap(wp[4], wp[6]); pswap(wp[5], wp[7]);
            u32x4 f0 = {wp[0], wp[1], wp[2], wp[3]};
            u32x4 f1 = {wp[4], wp[5], wp[6], wp[7]};
            pa[2 * tb]     = __builtin_bit_cast(bf16x8, f0);
            pa[2 * tb + 1] = __builtin_bit_cast(bf16x8, f1);
        }
        // O^T += V^T P^T (C cols are q = c -> lane-local rescale is exact)
#pragma unroll
        for (int ku = 0; ku < 4; ++ku) {
            st.o0 = mfma32(vr[0][ku], pa[ku], st.o0);
            st.o1 = mfma32(vr[1][ku], pa[ku], st.o1);
        }
    };

    bf16x8 kA[2][4], kB[2][4];
    int t = g8;
    kload(kA, t);
    for (;;) {
        body(kA, kB, t);
        t += 8; if (t >= NT) break;
        body(kB, kA, t);
        t += 8; if (t >= NT) break;
    }
}

__global__ __launch_bounds__(512, 2)
void attn(const unsigned short* __restrict__ Qf, const unsigned short* __restrict__ Kf,
          const unsigned short* __restrict__ Vf, float* __restrict__ Yg)
{
    __shared__ float Osm[8][QB][33];
    __shared__ float Msm[2][8][QB];
    __shared__ float Lsm[2][8][QB];

    const int tid = threadIdx.x;
    const int g8 = tid >> 6, l = tid & 63, h = l >> 5, c = l & 31;
    const int batch = blockIdx.x & 3;
    const int pr = blockIdx.x >> 2;
    const int qtA = pr, qtB = 127 - pr;

    TState sB, sA;
    run_tile(Qf, Kf, Vf, batch, qtB, g8, l, h, c, sB);
    run_tile(Qf, Kf, Vf, batch, qtA, g8, l, h, c, sA);

    if (h == 0) {
        Msm[0][g8][c] = sA.m; Lsm[0][g8][c] = sA.l;
        Msm[1][g8][c] = sB.m; Lsm[1][g8][c] = sB.l;
    }

    auto write_partial = [&](const f16v& o) {
#pragma unroll
        for (int r = 0; r < 16; ++r) {
            int dd = (r & 3) + 8 * (r >> 2) + 4 * h;
            Osm[g8][c][dd] = o[r];
        }
    };
    auto merge_phase = [&](int tile, int dhalf, int qt_) {
        const int q = tid >> 4, d2 = (tid & 15) * 2;
        float mm = -1e30f;
#pragma unroll
        for (int gg = 0; gg < 8; ++gg) mm = fmaxf(mm, Msm[tile][gg][q]);
        float L = 0.f, o0 = 0.f, o1 = 0.f;
#pragma unroll
        for (int gg = 0; gg < 8; ++gg) {
            float a = exp2f(Msm[tile][gg][q] - mm);
            L += a * Lsm[tile][gg][q];
            o0 += a * Osm[gg][q][d2];
            o1 += a * Osm[gg][q][d2 + 1];
        }
        float inv = 1.f / L;
        float* yp = Yg + ((size_t)batch * TSEQ + (size_t)qt_ * QB + q) * HDIM + dhalf * 32 + d2;
        yp[0] = o0 * inv; yp[1] = o1 * inv;
    };

    write_partial(sA.o0);
    __syncthreads();
    merge_phase(0, 0, qtA);
    __syncthreads();
    write_partial(sA.o1);
    __syncthreads();
    merge_phase(0, 1, qtA);
    __syncthreads();
    write_partial(sB.o0);
    __syncthreads();
    merge_phase(1, 0, qtB);
    __syncthreads();
    write_partial(sB.o1);
    __syncthreads();
    merge_phase(1, 1, qtB);
}

extern "C" void kernel_launch(void* const* d_in, const int* in_sizes, int n_in,
                              void* d_out, int out_size, void* d_ws, size_t ws_size,
                              hipStream_t stream)
{
    const float* x  = (const float*)d_in[0];
    const float* Wq = (const float*)d_in[1];
    const float* bq = (const float*)d_in[2];
    const float* Wk = (const float*)d_in[3];
    const float* bk = (const float*)d_in[4];
    const float* Wv = (const float*)d_in[5];
    const float* bv = (const float*)d_in[6];
    float* y = (float*)d_out;

    unsigned short* Qb = (unsigned short*)d_ws;          // 1M bf16 (frag order)
    unsigned short* Kb = Qb + (size_t)1048576;           // 1M bf16
    unsigned short* Vb = Kb + (size_t)1048576;           // 1M bf16
    unsigned short* Wf = Vb + (size_t)1048576;           // 196608 fp16 (pad to 256K)
    unsigned short* xf = Wf + (size_t)262144;            // 16M fp16 (frag order, 32MB)

    fused_prep<<<2112, 256, 0, stream>>>(x, Wq, Wk, Wv, Wf, xf);
    projf<<<512, 256, 0, stream>>>(xf, Wf, bq, bk, bv, Qb, Kb, Vb);
    attn<<<256, 512, 0, stream>>>(Qb, Kb, Vb, y);
}

// Round 11
// 50.433 us; speedup vs baseline: 1.1751x; 1.1751x over previous
//
#include <hip/hip_runtime.h>
#include <hip/hip_bf16.h>

typedef __attribute__((ext_vector_type(4))) float f4v;
typedef __attribute__((ext_vector_type(16))) float f16v;
typedef __attribute__((ext_vector_type(4))) unsigned short u16x4;
typedef __attribute__((ext_vector_type(8))) unsigned short u16x8;
typedef __attribute__((ext_vector_type(4))) unsigned int u32x4;
typedef __attribute__((ext_vector_type(8))) __bf16 bf16x8;
typedef __attribute__((ext_vector_type(8))) _Float16 h8v;

#define D_MODEL 1024
#define HDIM 64
#define TSEQ 4096
#define QB 32
#define KVB 64
// 1/sqrt(HDIM) * log2(e), folded into Q at projection
#define QSCALE 0.18033688011112042f

__device__ __forceinline__ unsigned short f2bf(float f) {
    union { float f; unsigned u; } v; v.f = f;
    unsigned r = v.u + 0x7FFFu + ((v.u >> 16) & 1u);
    return (unsigned short)(r >> 16);
}
__device__ __forceinline__ bf16x8 ld8(const unsigned short* p) {
    return __builtin_bit_cast(bf16x8, *(const u16x8*)p);
}
__device__ __forceinline__ h8v ldh8(const unsigned short* p) {
    return __builtin_bit_cast(h8v, *(const u16x8*)p);
}
__device__ __forceinline__ f4v mfma16f(h8v a, h8v b, f4v c) {
    return __builtin_amdgcn_mfma_f32_16x16x32_f16(a, b, c, 0, 0, 0);
}
__device__ __forceinline__ f16v mfma32(bf16x8 a, bf16x8 b, f16v c) {
    return __builtin_amdgcn_mfma_f32_32x32x16_bf16(a, b, c, 0, 0, 0);
}
__device__ __forceinline__ unsigned cvtpk(float a, float b) {
    unsigned r;
    asm("v_cvt_pk_bf16_f32 %0, %1, %2" : "=v"(r) : "v"(a), "v"(b));
    return r;
}
__device__ __forceinline__ void pswap(unsigned& a, unsigned& b) {
    asm("v_permlane32_swap_b32 %0, %1" : "+v"(a), "+v"(b));
}
__device__ __forceinline__ h8v pack8(f4v a, f4v b) {
    unsigned p0 = __builtin_bit_cast(unsigned, __builtin_amdgcn_cvt_pkrtz(a[0], a[1]));
    unsigned p1 = __builtin_bit_cast(unsigned, __builtin_amdgcn_cvt_pkrtz(a[2], a[3]));
    unsigned p2 = __builtin_bit_cast(unsigned, __builtin_amdgcn_cvt_pkrtz(b[0], b[1]));
    unsigned p3 = __builtin_bit_cast(unsigned, __builtin_amdgcn_cvt_pkrtz(b[2], b[3]));
    u32x4 u = {p0, p1, p2, p3};
    return __builtin_bit_cast(h8v, u);
}

// ---------- W -> fragment-order fp16: Wf[m][kstep(32)][nf(4)][lane(64)][8] ----------
// element = W[m][k = kstep*32 + 8*(lane>>4) + j][n = nf*16 + (lane&15)]
__global__ void prep_wf(const float* __restrict__ Wq, const float* __restrict__ Wk,
                        const float* __restrict__ Wv, unsigned short* __restrict__ Wf)
{
    int idx = blockIdx.x * 256 + threadIdx.x;   // < 196608
    int j = idx & 7, lane = (idx >> 3) & 63, nf = (idx >> 9) & 3,
        kstep = (idx >> 11) & 31, m = idx >> 16;
    int k = kstep * 32 + 8 * (lane >> 4) + j;
    int n = nf * 16 + (lane & 15);
    const float* W = (m == 0) ? Wq : (m == 1) ? Wk : Wv;
    _Float16 hv = (_Float16)W[k * 64 + n];
    Wf[idx] = __builtin_bit_cast(unsigned short, hv);
}

// ---------- QKV projection ----------
// 512 blocks x 256 thr, BM=32 rows, BK=64, 16 iters, 2 blocks/CU.
// ALL inner-loop operands come from LDS (the r1-r3 property that measured
// fastest); both x (HBM, 8KB/iter) and W (L2, 24KB/iter) are staged via
// global_load_lds, double-buffered, one end-of-iter barrier = full-compute
// prefetch distance (m97 schedule). x granules source-XOR-swizzled
// (g ^= row&7) so the frag-order b128 reads are conflict-free.
// fp16 single-pass MFMA. Outputs in MFMA-fragment order for attn.
__global__ __launch_bounds__(256, 2)
void proj_qkv(const float* __restrict__ x, const unsigned short* __restrict__ Wf,
              const float* __restrict__ bq, const float* __restrict__ bk,
              const float* __restrict__ bv,
              unsigned short* __restrict__ Qf, unsigned short* __restrict__ Kf,
              unsigned short* __restrict__ Vf)
{
    __shared__ float xs[2][2048];            // [buf][row(32) * 64 floats] = 8KB each
    __shared__ unsigned short wl[2][12288];  // [buf][chunk(24)][lane*8] = 24KB each

    const int tid = threadIdx.x;
    const int w = tid >> 6, l = tid & 63;
    const int row0 = blockIdx.x * 32;

    f4v acc[2][3];
#pragma unroll
    for (int s = 0; s < 2; ++s)
#pragma unroll
        for (int f = 0; f < 3; ++f) acc[s][f] = (f4v)0.f;

    // stage x tile t (32 rows x 64 floats = 8KB, 512 granules of 16B):
    // linear dest granule G -> logical (row = G>>4, granule (G&15)^(row&7)).
    // stage W chunk t (24 frag-chunks x 1KB = 24KB): chunk = cf*2+ks,
    // kglob = t*2+ks; linear dest, contiguous source.
    auto stage = [&](int buf, int t) {
#pragma unroll
        for (int j = 0; j < 2; ++j) {
            const int G = j * 256 + tid;
            const int row = G >> 4;
            const int gl = (G & 15) ^ (row & 7);
            const float* src = x + (size_t)(row0 + row) * D_MODEL + t * 64 + gl * 4;
            __builtin_amdgcn_global_load_lds(
                (const __attribute__((address_space(1))) unsigned*)src,
                (__attribute__((address_space(3))) unsigned*)&xs[buf][G * 4],
                16, 0, 0);
        }
#pragma unroll
        for (int j = 0; j < 6; ++j) {
            const int chunk = j * 4 + w;           // 0..23
            const int cf = chunk >> 1, ks = chunk & 1;
            const unsigned short* src =
                Wf + ((((cf >> 2) * 32 + (t * 2 + ks)) * 4 + (cf & 3)) << 9) + l * 8;
            __builtin_amdgcn_global_load_lds(
                (const __attribute__((address_space(1))) unsigned*)src,
                (__attribute__((address_space(3))) unsigned*)&wl[buf][chunk * 512],
                16, 0, 0);
        }
    };

    stage(0, 0);
    __syncthreads();

#pragma unroll
    for (int t = 0; t < 16; ++t) {
        if (t < 15) stage((t + 1) & 1, t + 1);
        const int b = t & 1;
        const int sw = l & 7;
#pragma unroll
        for (int ks = 0; ks < 2; ++ks) {
            h8v bw[3];
#pragma unroll
            for (int f = 0; f < 3; ++f) {
                const int cf = w * 3 + f;
                bw[f] = ldh8(&wl[b][(cf * 2 + ks) * 512 + l * 8]);
            }
            const int gr = ks * 8 + 2 * (l >> 4);
#pragma unroll
            for (int s = 0; s < 2; ++s) {
                const int row = s * 16 + (l & 15);
                f4v a0 = *(const f4v*)&xs[b][row * 64 + ((gr ^ sw) << 2)];
                f4v a1 = *(const f4v*)&xs[b][row * 64 + (((gr + 1) ^ sw) << 2)];
                h8v xa = pack8(a0, a1);
#pragma unroll
                for (int f = 0; f < 3; ++f)
                    acc[s][f] = mfma16f(xa, bw[f], acc[s][f]);
            }
        }
        __syncthreads();
    }

    const float* bias[3] = {bq, bk, bv};
#pragma unroll
    for (int s = 0; s < 2; ++s) {
        const int rowb = row0 + s * 16 + 4 * (l >> 4);
        const int b = rowb >> 12, tok0 = rowb & 4095;
#pragma unroll
        for (int f = 0; f < 3; ++f) {
            const int cf = w * 3 + f;
            const int m = cf >> 2, nf = cf & 3;
            const int d = nf * 16 + (l & 15);
            const float bb = bias[m][d];
            if (m == 0) {
                const int qtile = tok0 >> 5;
                const int ksq = d >> 4, hq = (d >> 3) & 1, jq = d & 7;
#pragma unroll
                for (int r4 = 0; r4 < 4; ++r4) {
                    int cq = (tok0 & 31) + r4;
                    Qf[(((size_t)(b * 128 + qtile) * 4 + ksq) << 9) + (32 * hq + cq) * 8 + jq] =
                        f2bf((acc[s][f][r4] + bb) * QSCALE);
                }
            } else if (m == 1) {
                const int t = tok0 >> 6, tb = (tok0 >> 5) & 1;
                const int ksk = d >> 4, hk = (d >> 3) & 1, jk = d & 7;
#pragma unroll
                for (int r4 = 0; r4 < 4; ++r4) {
                    int ck = (tok0 & 31) + r4;
                    Kf[(((size_t)((b * 64 + t) * 8 + tb * 4 + ksk)) << 9) + (32 * hk + ck) * 8 + jk] =
                        f2bf(acc[s][f][r4] + bb);
                }
            } else {
                // Vf element (lane', j) = V[kv = t*64 + 16ku + 8hv + j][dv = 32td + c']
                const int t = tok0 >> 6, ku = (tok0 >> 4) & 3, hv = (tok0 >> 3) & 1, jv = tok0 & 7;
                const int cv = d & 31, td = d >> 5;
                u16x4 pk;
#pragma unroll
                for (int r4 = 0; r4 < 4; ++r4) pk[r4] = f2bf(acc[s][f][r4] + bb);
                *(u16x4*)(Vf + (((size_t)((b * 64 + t) * 8 + td * 4 + ku)) << 9) +
                          (32 * hv + cv) * 8 + jv) = pk;
            }
        }
    }
}

// ---------- flash attention ----------
// 256 blocks (4 batch x 64 q-tile PAIRS {pr, 127-pr}: constant work) x 8 waves.
// batch = bid&3 -> each XCD sees one batch -> K/V L2-resident.
// Wave g handles kv tiles t = g, g+8, ... for BOTH q-tiles -> balanced per wave.
// All operand loads are 1KB coalesced ld8 from fragment-order Qf/Kf/Vf.
struct TState { float m, l; f16v o0, o1; };

__device__ __forceinline__ void run_tile(const unsigned short* __restrict__ Qf,
                                         const unsigned short* __restrict__ Kf,
                                         const unsigned short* __restrict__ Vf,
                                         int batch, int qt, int g8, int l, int h, int c,
                                         TState& st)
{
    const int NT = (qt >> 1) + 1;
    st.m = -1e30f; st.l = 0.f; st.o0 = (f16v)0.f; st.o1 = (f16v)0.f;

    bf16x8 qf[4];
    const unsigned short* qp = Qf + (((size_t)(batch * 128 + qt) * 4) << 9) + l * 8;
#pragma unroll
    for (int ks = 0; ks < 4; ++ks) qf[ks] = ld8(qp + (ks << 9));

    if (g8 >= NT) return;

    auto kload = [&](bf16x8(&kr)[2][4], int t_) {
        const unsigned short* p = Kf + (((size_t)(batch * 64 + t_) * 8) << 9) + l * 8;
#pragma unroll
        for (int tb = 0; tb < 2; ++tb)
#pragma unroll
            for (int ks = 0; ks < 4; ++ks)
                kr[tb][ks] = ld8(p + ((tb * 4 + ks) << 9));
    };

    auto body = [&](bf16x8(&kr)[2][4], bf16x8(&kn)[2][4], int t_) {
        bf16x8 vr[2][4];
        {
            const unsigned short* p = Vf + (((size_t)(batch * 64 + t_) * 8) << 9) + l * 8;
#pragma unroll
            for (int td = 0; td < 2; ++td)
#pragma unroll
                for (int ku = 0; ku < 4; ++ku)
                    vr[td][ku] = ld8(p + ((td * 4 + ku) << 9));
        }
        // S^T = K Q^T
        f16v sacc[2];
        sacc[0] = (f16v)0.f; sacc[1] = (f16v)0.f;
#pragma unroll
        for (int ks = 0; ks < 4; ++ks) {
            sacc[0] = mfma32(kr[0][ks], qf[ks], sacc[0]);
            sacc[1] = mfma32(kr[1][ks], qf[ks], sacc[1]);
        }
        int tn = t_ + 8; if (tn > NT - 1) tn = NT - 1;
        kload(kn, tn);
        if (t_ == NT - 1) {   // causal mask on diagonal tile
            const int off = qt * QB - t_ * KVB;
#pragma unroll
            for (int tb = 0; tb < 2; ++tb)
#pragma unroll
                for (int r = 0; r < 16; ++r) {
                    int mv = 32 * tb + (r & 3) + 8 * (r >> 2) + 4 * h - off;
                    if (mv > c) sacc[tb][r] = -1e30f;
                }
        }
        // online softmax (exp2 domain)
        float pm = -1e30f;
#pragma unroll
        for (int tb = 0; tb < 2; ++tb)
#pragma unroll
            for (int r = 0; r < 16; ++r) pm = fmaxf(pm, sacc[tb][r]);
        pm = fmaxf(pm, __shfl_xor(pm, 32));
        const float mnew = fmaxf(st.m, pm);
        const float sc = exp2f(st.m - mnew);
        st.m = mnew;
        float rs = 0.f;
        float p[2][16];
#pragma unroll
        for (int tb = 0; tb < 2; ++tb)
#pragma unroll
            for (int r = 0; r < 16; ++r) {
                float e = exp2f(sacc[tb][r] - mnew);
                p[tb][r] = e; rs += e;
            }
        rs += __shfl_xor(rs, 32);
        st.l = st.l * sc + rs;
#pragma unroll
        for (int r = 0; r < 16; ++r) { st.o0[r] *= sc; st.o1[r] *= sc; }
        // P (C-layout) -> frag via cvt_pk + permlane32_swap
        bf16x8 pa[4];
#pragma unroll
        for (int tb = 0; tb < 2; ++tb) {
            unsigned wp[8];
#pragma unroll
            for (int i = 0; i < 8; ++i) wp[i] = cvtpk(p[tb][2 * i], p[tb][2 * i + 1]);
            pswap(wp[0], wp[2]); pswap(wp[1], wp[3]);
            pswap(wp[4], wp[6]); pswap(wp[5], wp[7]);
            u32x4 f0 = {wp[0], wp[1], wp[2], wp[3]};
            u32x4 f1 = {wp[4], wp[5], wp[6], wp[7]};
            pa[2 * tb]     = __builtin_bit_cast(bf16x8, f0);
            pa[2 * tb + 1] = __builtin_bit_cast(bf16x8, f1);
        }
        // O^T += V^T P^T (C cols are q = c -> lane-local rescale is exact)
#pragma unroll
        for (int ku = 0; ku < 4; ++ku) {
            st.o0 = mfma32(vr[0][ku], pa[ku], st.o0);
            st.o1 = mfma32(vr[1][ku], pa[ku], st.o1);
        }
    };

    bf16x8 kA[2][4], kB[2][4];
    int t = g8;
    kload(kA, t);
    for (;;) {
        body(kA, kB, t);
        t += 8; if (t >= NT) break;
        body(kB, kA, t);
        t += 8; if (t >= NT) break;
    }
}

__global__ __launch_bounds__(512, 2)
void attn(const unsigned short* __restrict__ Qf, const unsigned short* __restrict__ Kf,
          const unsigned short* __restrict__ Vf, float* __restrict__ Yg)
{
    __shared__ float Osm[8][QB][33];
    __shared__ float Msm[2][8][QB];
    __shared__ float Lsm[2][8][QB];

    const int tid = threadIdx.x;
    const int g8 = tid >> 6, l = tid & 63, h = l >> 5, c = l & 31;
    const int batch = blockIdx.x & 3;
    const int pr = blockIdx.x >> 2;
    const int qtA = pr, qtB = 127 - pr;

    TState sB, sA;
    run_tile(Qf, Kf, Vf, batch, qtB, g8, l, h, c, sB);
    run_tile(Qf, Kf, Vf, batch, qtA, g8, l, h, c, sA);

    if (h == 0) {
        Msm[0][g8][c] = sA.m; Lsm[0][g8][c] = sA.l;
        Msm[1][g8][c] = sB.m; Lsm[1][g8][c] = sB.l;
    }

    auto write_partial = [&](const f16v& o) {
#pragma unroll
        for (int r = 0; r < 16; ++r) {
            int dd = (r & 3) + 8 * (r >> 2) + 4 * h;
            Osm[g8][c][dd] = o[r];
        }
    };
    auto merge_phase = [&](int tile, int dhalf, int qt_) {
        const int q = tid >> 4, d2 = (tid & 15) * 2;
        float mm = -1e30f;
#pragma unroll
        for (int gg = 0; gg < 8; ++gg) mm = fmaxf(mm, Msm[tile][gg][q]);
        float L = 0.f, o0 = 0.f, o1 = 0.f;
#pragma unroll
        for (int gg = 0; gg < 8; ++gg) {
            float a = exp2f(Msm[tile][gg][q] - mm);
            L += a * Lsm[tile][gg][q];
            o0 += a * Osm[gg][q][d2];
            o1 += a * Osm[gg][q][d2 + 1];
        }
        float inv = 1.f / L;
        float* yp = Yg + ((size_t)batch * TSEQ + (size_t)qt_ * QB + q) * HDIM + dhalf * 32 + d2;
        yp[0] = o0 * inv; yp[1] = o1 * inv;
    };

    write_partial(sA.o0);
    __syncthreads();
    merge_phase(0, 0, qtA);
    __syncthreads();
    write_partial(sA.o1);
    __syncthreads();
    merge_phase(0, 1, qtA);
    __syncthreads();
    write_partial(sB.o0);
    __syncthreads();
    merge_phase(1, 0, qtB);
    __syncthreads();
    write_partial(sB.o1);
    __syncthreads();
    merge_phase(1, 1, qtB);
}

extern "C" void kernel_launch(void* const* d_in, const int* in_sizes, int n_in,
                              void* d_out, int out_size, void* d_ws, size_t ws_size,
                              hipStream_t stream)
{
    const float* x  = (const float*)d_in[0];
    const float* Wq = (const float*)d_in[1];
    const float* bq = (const float*)d_in[2];
    const float* Wk = (const float*)d_in[3];
    const float* bk = (const float*)d_in[4];
    const float* Wv = (const float*)d_in[5];
    const float* bv = (const float*)d_in[6];
    float* y = (float*)d_out;

    unsigned short* Qb = (unsigned short*)d_ws;          // 1M bf16 (frag order)
    unsigned short* Kb = Qb + (size_t)1048576;           // 1M bf16
    unsigned short* Vb = Kb + (size_t)1048576;           // 1M bf16
    unsigned short* Wf = Vb + (size_t)1048576;           // 196608 fp16

    prep_wf<<<768, 256, 0, stream>>>(Wq, Wk, Wv, Wf);
    proj_qkv<<<512, 256, 0, stream>>>(x, Wf, bq, bk, bv, Qb, Kb, Vb);
    attn<<<256, 512, 0, stream>>>(Qb, Kb, Vb, y);
}